// Round 12
// baseline (225.912 us; speedup 1.0000x reference)
//
#include <hip/hip_runtime.h>
#include <hip/hip_bf16.h>
#include <stdint.h>

#define DIN   4096
#define DOUT  4096
#define MTOT  8192

#define BK    64
#define NKT   (DIN / BK)   // 64 K-tiles

typedef int i32x4 __attribute__((ext_vector_type(4)));

__device__ __forceinline__ void glds16(const void* g, void* l) {
  __builtin_amdgcn_global_load_lds(
      (__attribute__((address_space(1))) void*)g,
      (__attribute__((address_space(3))) void*)l, 16, 0, 0);
}

// ---------------------------------------------------------------------------
// Kernel 1: per-row alpha (fp64 accumulate) + ternary quantize -> i8 {-1,0,1}
// ---------------------------------------------------------------------------
__global__ __launch_bounds__(256) void quant_w(const float* __restrict__ W,
                                               int8_t* __restrict__ QW) {
  const int row = blockIdx.x;
  const int t = threadIdx.x;
  const float* wr = W + (size_t)row * DIN;

  float4 v[4];
  double s = 0.0;
#pragma unroll
  for (int j = 0; j < 4; ++j) {
    v[j] = reinterpret_cast<const float4*>(wr)[j * 256 + t];
    s += (double)fabsf(v[j].x) + (double)fabsf(v[j].y) +
         (double)fabsf(v[j].z) + (double)fabsf(v[j].w);
  }
#pragma unroll
  for (int off = 32; off > 0; off >>= 1) s += __shfl_down(s, off, 64);

  __shared__ double ssum[4];
  __shared__ float salpha;
  if ((t & 63) == 0) ssum[t >> 6] = s;
  __syncthreads();
  if (t == 0) salpha = (float)((ssum[0] + ssum[1] + ssum[2] + ssum[3]) / (double)DIN);
  __syncthreads();
  const float alpha = salpha;

  int* qo = reinterpret_cast<int*>(QW + (size_t)row * DIN);
#pragma unroll
  for (int j = 0; j < 4; ++j) {
    int q0 = v[j].x > alpha ? 1 : (v[j].x < -alpha ? -1 : 0);
    int q1 = v[j].y > alpha ? 1 : (v[j].y < -alpha ? -1 : 0);
    int q2 = v[j].z > alpha ? 1 : (v[j].z < -alpha ? -1 : 0);
    int q3 = v[j].w > alpha ? 1 : (v[j].w < -alpha ? -1 : 0);
    qo[j * 256 + t] =
        (q0 & 0xff) | ((q1 & 0xff) << 8) | ((q2 & 0xff) << 16) | ((q3 & 0xff) << 24);
  }
}

// ---------------------------------------------------------------------------
// Kernel 2: x fp32 -> i8 with per-row scale. xq = rint(x * 127/rowmax),
// XS[row] = rowmax/127.
// ---------------------------------------------------------------------------
__global__ __launch_bounds__(256) void quant_x(const float* __restrict__ X,
                                               int8_t* __restrict__ XQ,
                                               float* __restrict__ XS) {
  const int row = blockIdx.x;
  const int t = threadIdx.x;
  const float* xr = X + (size_t)row * DIN;

  float4 v[4];
  float mx = 0.f;
#pragma unroll
  for (int j = 0; j < 4; ++j) {
    v[j] = reinterpret_cast<const float4*>(xr)[j * 256 + t];
    mx = fmaxf(mx, fmaxf(fmaxf(fabsf(v[j].x), fabsf(v[j].y)),
                         fmaxf(fabsf(v[j].z), fabsf(v[j].w))));
  }
#pragma unroll
  for (int off = 32; off > 0; off >>= 1) mx = fmaxf(mx, __shfl_down(mx, off, 64));

  __shared__ float smax[4];
  __shared__ float sinv, ssc;
  if ((t & 63) == 0) smax[t >> 6] = mx;
  __syncthreads();
  if (t == 0) {
    float rm = fmaxf(fmaxf(smax[0], smax[1]), fmaxf(smax[2], smax[3]));
    sinv = rm > 0.f ? 127.f / rm : 0.f;
    ssc  = rm > 0.f ? rm / 127.f : 0.f;
  }
  __syncthreads();
  const float inv = sinv;
  if (t == 0) XS[row] = ssc;

  int* qo = reinterpret_cast<int*>(XQ + (size_t)row * DIN);
#pragma unroll
  for (int j = 0; j < 4; ++j) {
    int q0 = (int)rintf(v[j].x * inv);
    int q1 = (int)rintf(v[j].y * inv);
    int q2 = (int)rintf(v[j].z * inv);
    int q3 = (int)rintf(v[j].w * inv);
    qo[j * 256 + t] =
        (q0 & 0xff) | ((q1 & 0xff) << 8) | ((q2 & 0xff) << 16) | ((q3 & 0xff) << 24);
  }
}

// ---------------------------------------------------------------------------
// Kernel 3: 128x128 i8 MFMA GEMM (mfma_i32_16x16x64_i8), round-12:
// occupancy-first geometry. 256 thr = 4 waves (2Mx2N), wave owns 64x64
// (acc = 16 x i32x4 = 64 AGPR), LDS 32 KB/block -> 4 blocks/CU, 4 waves/SIMD,
// FOUR independent barrier domains per CU (stall overlap across blocks).
//
// 2 windows/tile (r11-proven invariant):
//   ph1: read a[4]+b[4] (8 ds_read); ISSUE A(T+1) [2 glds];
//        MMA ni={0,1} (8); lgkm0 (drains b23, consumed ph2); BAR
//   ph2: ISSUE B(T+2) [2 glds]; MMA ni={2,3} (8); vmcnt(2|0); BAR
//
// Overwrite audit:
//   A(T+1)->As[buf^1]@ph1: all As[buf^1] reads were (T-1).ph1, consumed by
//     (T-1) MMA and drained at (T-1).ph1's lgkm0; issuer crossed >=2 BARs. OK
//   B(T+2)->Bs[buf]@ph2: all Bs[buf] reads at T.ph1, consumed (b01) or
//     drained by ph1's lgkm0 (b23), before ph1's BAR; issue after.       OK
//   Tile T+1 reads gated by T.ph2's vmcnt+BAR.                           OK
// vmcnt ledger (stream: ...B(T+1)@(T-1).ph2 < A(T+1)@T.ph1 < B(T+2)@T.ph2):
//   at T.ph2 wait, only B(T+2)'s 2 loads trail A(T+1) -> vmcnt(2) ==
//   A(T+1), B(T+1) landed. vmcnt(0) for T >= NKT-2.
// Swizzle: identical to r11 (16B chunk ^ (row>>1)&3; measured 0 conflicts).
// ---------------------------------------------------------------------------
__global__ __launch_bounds__(256, 4) void gemm128_i8(
    const int8_t* __restrict__ XQ, const int8_t* __restrict__ QW,
    const float* __restrict__ XS, const float* __restrict__ scale,
    const float* __restrict__ bias, float* __restrict__ out) {
  __shared__ int8_t As[2][8192];  // 8 KB each buf (128 rows x 64 B)
  __shared__ int8_t Bs[2][8192];

  const int t = threadIdx.x;
  const int lane = t & 63;
  const int wid = t >> 6;
  const int wr = wid >> 1, wc = wid & 1;          // 2x2 wave grid
  const int m0 = blockIdx.x * 128;                // m fast-varying
  const int n0 = blockIdx.y * 128;

  const int8_t* ag = XQ + (size_t)m0 * DIN;
  const int8_t* bg = QW + (size_t)n0 * DIN;

  i32x4 acc[4][4] = {};            // [m-frag][n-frag], 64 AGPRs
  i32x4 a[4], b[4];

  const int r = lane & 15, kq = lane >> 4;        // frag row / 16B k-chunk

// issue one 128x64 operand tile (2 glds16/thread): is_b selects B
#define ISSUE_T(Tt_, isb_) do {                                                 \
    const int T_ = (Tt_);                                                       \
    if (T_ < NKT) {                                                             \
      const int bf_ = T_ & 1;                                                   \
      const int8_t* gb_ = (isb_) ? bg : ag;                                     \
      int8_t* lb_ = (isb_) ? &Bs[bf_][0] : &As[bf_][0];                         \
      _Pragma("unroll")                                                         \
      for (int i_ = 0; i_ < 2; ++i_) {                                          \
        const int row_ = i_ * 64 + (t >> 2);                                    \
        const int scol_ = ((t & 3) ^ ((row_ >> 1) & 3)) * 16;                   \
        glds16(gb_ + (size_t)row_ * DIN + T_ * 64 + scol_,                      \
               lb_ + i_ * 4096 + t * 16);                                       \
      }                                                                         \
    }                                                                           \
  } while (0)

#define READA(buf_) do {                                                        \
    _Pragma("unroll")                                                           \
    for (int mi = 0; mi < 4; ++mi) {                                            \
      const int row_ = wr * 64 + mi * 16 + r;                                   \
      a[mi] = *reinterpret_cast<const i32x4*>(                                  \
          &As[buf_][row_ * 64 + (kq ^ ((row_ >> 1) & 3)) * 16]);                \
    }                                                                           \
  } while (0)

#define READB(buf_) do {                                                        \
    _Pragma("unroll")                                                           \
    for (int ni = 0; ni < 4; ++ni) {                                            \
      const int row_ = wc * 64 + ni * 16 + r;                                   \
      b[ni] = *reinterpret_cast<const i32x4*>(                                  \
          &Bs[buf_][row_ * 64 + (kq ^ ((row_ >> 1) & 3)) * 16]);                \
    }                                                                           \
  } while (0)

// 8 MFMA: all 4 m-frags x n-frags {nh*2, nh*2+1}
#define MMA8(nh_) do {                                                          \
    __builtin_amdgcn_s_setprio(1);                                              \
    _Pragma("unroll")                                                           \
    for (int mi = 0; mi < 4; ++mi) {                                            \
      _Pragma("unroll")                                                         \
      for (int ni = 0; ni < 2; ++ni) {                                          \
        acc[mi][(nh_) * 2 + ni] =                                               \
            __builtin_amdgcn_mfma_i32_16x16x64_i8(                              \
                a[mi], b[(nh_) * 2 + ni], acc[mi][(nh_) * 2 + ni], 0, 0, 0);    \
      }                                                                         \
    }                                                                           \
    __builtin_amdgcn_s_setprio(0);                                              \
  } while (0)

#define BAR() __builtin_amdgcn_s_barrier()
#define LGKM0() asm volatile("s_waitcnt lgkmcnt(0)" ::: "memory")

#define TILE(T_, buf_) do {                                                     \
    /* ph1 */                                                                   \
    READA(buf_);                                                                \
    READB(buf_);                                                                \
    ISSUE_T((T_) + 1, 0);                                                       \
    MMA8(0);                                                                    \
    LGKM0();  /* drain b23 (consumed ph2) before BAR: overwrite anchor */       \
    BAR();                                                                      \
    /* ph2 */                                                                   \
    ISSUE_T((T_) + 2, 1);                                                       \
    MMA8(1);                                                                    \
    if ((T_) < NKT - 2)                                                         \
      asm volatile("s_waitcnt vmcnt(2)" ::: "memory");                          \
    else                                                                        \
      asm volatile("s_waitcnt vmcnt(0)" ::: "memory");                          \
    BAR();                                                                      \
  } while (0)

  // prologue: A(0), B(0), B(1) — 6 loads, stream order matches steady state.
  // vmcnt(2) => A(0), B(0) landed (B(1) may remain in flight).
  ISSUE_T(0, 0); ISSUE_T(0, 1); ISSUE_T(1, 1);
  asm volatile("s_waitcnt vmcnt(2)" ::: "memory");
  __builtin_amdgcn_s_barrier();

  for (int T = 0; T < NKT; T += 2) {
    TILE(T, 0);
    TILE(T + 1, 1);
  }

  // epilogue: C/D lane map col=lane&15, row=(lane>>4)*4+e (dtype-independent)
  const int q4 = lane >> 4;
#pragma unroll
  for (int ni = 0; ni < 4; ++ni) {
    const int col = n0 + wc * 64 + ni * 16 + r;
    const float sc = scale[col];
    const float bs = bias[col];
#pragma unroll
    for (int mi = 0; mi < 4; ++mi) {
      const int row = m0 + wr * 64 + mi * 16 + q4 * 4;
#pragma unroll
      for (int e = 0; e < 4; ++e) {
        const float xs = XS[row + e];
        out[(size_t)(row + e) * DOUT + col] =
            (float)acc[mi][ni][e] * (xs * sc) + bs;
      }
    }
  }
#undef ISSUE_T
#undef READA
#undef READB
#undef MMA8
#undef BAR
#undef LGKM0
#undef TILE
}

extern "C" void kernel_launch(void* const* d_in, const int* in_sizes, int n_in,
                              void* d_out, int out_size, void* d_ws, size_t ws_size,
                              hipStream_t stream) {
  const float* X     = (const float*)d_in[0];
  const float* W     = (const float*)d_in[1];
  const float* scale = (const float*)d_in[2];
  const float* bias  = (const float*)d_in[3];
  float* out = (float*)d_out;

  // ws layout: QW i8 16 MB | XQ i8 32 MB | XS fp32 32 KB
  int8_t* QW = (int8_t*)d_ws;
  int8_t* XQ = (int8_t*)d_ws + (size_t)DOUT * DIN;
  float*  XS = (float*)((int8_t*)d_ws + (size_t)DOUT * DIN + (size_t)MTOT * DIN);

  quant_w<<<DOUT, 256, 0, stream>>>(W, QW);
  quant_x<<<MTOT, 256, 0, stream>>>(X, XQ, XS);
  dim3 grid(MTOT / 128, DOUT / 128);
  gemm128_i8<<<grid, 256, 0, stream>>>(XQ, QW, XS, scale, bias, out);
}

// Round 13
// 206.750 us; speedup vs baseline: 1.0927x; 1.0927x over previous
//
#include <hip/hip_runtime.h>
#include <hip/hip_bf16.h>
#include <stdint.h>

#define DIN   4096
#define DOUT  4096
#define MTOT  8192

#define BK    64
#define NKT   (DIN / BK)   // 64 K-tiles

typedef int i32x4  __attribute__((ext_vector_type(4)));
typedef int i32x16 __attribute__((ext_vector_type(16)));

__device__ __forceinline__ void glds16(const void* g, void* l) {
  __builtin_amdgcn_global_load_lds(
      (__attribute__((address_space(1))) void*)g,
      (__attribute__((address_space(3))) void*)l, 16, 0, 0);
}

// ---------------------------------------------------------------------------
// Kernel 1: per-row alpha (fp64 accumulate) + ternary quantize -> i8 {-1,0,1}
// ---------------------------------------------------------------------------
__global__ __launch_bounds__(256) void quant_w(const float* __restrict__ W,
                                               int8_t* __restrict__ QW) {
  const int row = blockIdx.x;
  const int t = threadIdx.x;
  const float* wr = W + (size_t)row * DIN;

  float4 v[4];
  double s = 0.0;
#pragma unroll
  for (int j = 0; j < 4; ++j) {
    v[j] = reinterpret_cast<const float4*>(wr)[j * 256 + t];
    s += (double)fabsf(v[j].x) + (double)fabsf(v[j].y) +
         (double)fabsf(v[j].z) + (double)fabsf(v[j].w);
  }
#pragma unroll
  for (int off = 32; off > 0; off >>= 1) s += __shfl_down(s, off, 64);

  __shared__ double ssum[4];
  __shared__ float salpha;
  if ((t & 63) == 0) ssum[t >> 6] = s;
  __syncthreads();
  if (t == 0) salpha = (float)((ssum[0] + ssum[1] + ssum[2] + ssum[3]) / (double)DIN);
  __syncthreads();
  const float alpha = salpha;

  int* qo = reinterpret_cast<int*>(QW + (size_t)row * DIN);
#pragma unroll
  for (int j = 0; j < 4; ++j) {
    int q0 = v[j].x > alpha ? 1 : (v[j].x < -alpha ? -1 : 0);
    int q1 = v[j].y > alpha ? 1 : (v[j].y < -alpha ? -1 : 0);
    int q2 = v[j].z > alpha ? 1 : (v[j].z < -alpha ? -1 : 0);
    int q3 = v[j].w > alpha ? 1 : (v[j].w < -alpha ? -1 : 0);
    qo[j * 256 + t] =
        (q0 & 0xff) | ((q1 & 0xff) << 8) | ((q2 & 0xff) << 16) | ((q3 & 0xff) << 24);
  }
}

// ---------------------------------------------------------------------------
// Kernel 2: x fp32 -> i8 with per-row scale. xq = rint(x * 127/rowmax),
// XS[row] = rowmax/127.
// ---------------------------------------------------------------------------
__global__ __launch_bounds__(256) void quant_x(const float* __restrict__ X,
                                               int8_t* __restrict__ XQ,
                                               float* __restrict__ XS) {
  const int row = blockIdx.x;
  const int t = threadIdx.x;
  const float* xr = X + (size_t)row * DIN;

  float4 v[4];
  float mx = 0.f;
#pragma unroll
  for (int j = 0; j < 4; ++j) {
    v[j] = reinterpret_cast<const float4*>(xr)[j * 256 + t];
    mx = fmaxf(mx, fmaxf(fmaxf(fabsf(v[j].x), fabsf(v[j].y)),
                         fmaxf(fabsf(v[j].z), fabsf(v[j].w))));
  }
#pragma unroll
  for (int off = 32; off > 0; off >>= 1) mx = fmaxf(mx, __shfl_down(mx, off, 64));

  __shared__ float smax[4];
  __shared__ float sinv, ssc;
  if ((t & 63) == 0) smax[t >> 6] = mx;
  __syncthreads();
  if (t == 0) {
    float rm = fmaxf(fmaxf(smax[0], smax[1]), fmaxf(smax[2], smax[3]));
    sinv = rm > 0.f ? 127.f / rm : 0.f;
    ssc  = rm > 0.f ? rm / 127.f : 0.f;
  }
  __syncthreads();
  const float inv = sinv;
  if (t == 0) XS[row] = ssc;

  int* qo = reinterpret_cast<int*>(XQ + (size_t)row * DIN);
#pragma unroll
  for (int j = 0; j < 4; ++j) {
    int q0 = (int)rintf(v[j].x * inv);
    int q1 = (int)rintf(v[j].y * inv);
    int q2 = (int)rintf(v[j].z * inv);
    int q3 = (int)rintf(v[j].w * inv);
    qo[j * 256 + t] =
        (q0 & 0xff) | ((q1 & 0xff) << 8) | ((q2 & 0xff) << 16) | ((q3 & 0xff) << 24);
  }
}

// ---------------------------------------------------------------------------
// Kernel 3: 256x256 i8 MFMA GEMM, round-13: r11's EXACT 2-window sync
// skeleton, MFMA shape swapped to mfma_i32_32x32x32_i8 (peak-reaching shape,
// 4404 vs 3944 TOPS ubench; half the MFMA instruction count).
//
// 512 thr = 8 waves (2Mx4N), wave owns 128x64: m-frags 4 (32 rows), n-frags 2,
// ksteps 2 -> 16 MFMA/tile/wave, acc[4][2] x i32x16 = 128 AGPR.
// A frag (mi,ks): row=wr*128+mi*32+(lane&31), 16 B at k-byte (lane>>5)*16
// within kstep's 32-B chunk (byte pattern of verified bf16 32x32x16 port,
// same analogy that held for i8 16x16x64 in r9).
//
//   ph1: read aK0[4]+bK0[2]+bK1[2]; ISSUE A(T+1); MMA8(ks0);
//        lgkm0 (drains bK1, consumed ph2: overwrite anchor); BAR
//   ph2: read aK1[4];               ISSUE B(T+2); MMA8(ks1); vmcnt(2|0); BAR
//
// Overwrite audit:
//   A(T+1)->As[buf^1]@ph1: As[buf^1] reads were (T-1).ph1 (aK0, consumed) and
//     (T-1).ph2 (aK1, consumed); issuer crossed (T-1).ph2 BAR.            OK
//   B(T+2)->Bs[buf]@ph2: all Bs[buf] reads at T.ph1 (bK0 consumed, bK1
//     drained by ph1's lgkm0), before ph1's BAR; issue after.             OK
//   Tile T+1 reads gated by T.ph2's vmcnt+BAR.                            OK
// vmcnt ledger (stream: ...B(T+1)@(T-1).ph2 < A(T+1)@T.ph1 < B(T+2)@T.ph2):
//   at T.ph2 wait, only B(T+2)'s 2 loads trail A(T+1) -> vmcnt(2).
//   vmcnt(0) for T >= NKT-2.
// Swizzle: 16B chunk ^ ((row>>1)&3), unchanged (measured 0 conflicts).
// ---------------------------------------------------------------------------
__global__ __launch_bounds__(512, 2) void gemm256_i8(
    const int8_t* __restrict__ XQ, const int8_t* __restrict__ QW,
    const float* __restrict__ XS, const float* __restrict__ scale,
    const float* __restrict__ bias, float* __restrict__ out) {
  __shared__ int8_t As[2][16384];  // 16 KB each buf (256 rows x 64 B)
  __shared__ int8_t Bs[2][16384];

  const int t = threadIdx.x;
  const int lane = t & 63;
  const int wid = t >> 6;
  const int wr = wid >> 2, wc = wid & 3;          // 2x4 wave grid
  const int m0 = blockIdx.x * 256;                // m fast-varying
  const int n0 = blockIdx.y * 256;

  const int8_t* ag = XQ + (size_t)m0 * DIN;
  const int8_t* bg = QW + (size_t)n0 * DIN;

  i32x16 acc[4][2] = {};           // [m-frag][n-frag], 128 AGPRs
  i32x4 aK0[4], aK1[4];            // A frags ks=0 / ks=1
  i32x4 bK0[2], bK1[2];            // B frags ks=0 / ks=1

  const int l31 = lane & 31, lhi = lane >> 5;     // 32x32 frag row / k-half
  const int srow = t >> 2;                        // staging row 0..127
  const int scol = ((t & 3) ^ ((srow >> 1) & 3)) * 16;  // inverse-swizzled src

// issue one half-tile (1 glds16/thread): q: 0=A.h0 1=B.h0 2=A.h1 3=B.h1
#define ISSUE_H(Tt_, q_) do {                                                   \
    const int T_ = (Tt_);                                                       \
    if (T_ < NKT) {                                                             \
      const int q__ = (q_), hf_ = q__ >> 1, bf_ = T_ & 1;                       \
      const int8_t* gb_ = (q__ & 1) ? bg : ag;                                  \
      int8_t* lb_ = (q__ & 1) ? &Bs[bf_][0] : &As[bf_][0];                      \
      glds16(gb_ + (size_t)(hf_ * 128 + srow) * DIN + T_ * 64 + scol,           \
             lb_ + hf_ * 8192 + t * 16);                                        \
    }                                                                           \
  } while (0)

// A frag read: 16 B at chunk (ks*2 + lhi) of row wr*128+mi*32+l31
#define READA_K(dst_, buf_, ks_) do {                                           \
    _Pragma("unroll")                                                           \
    for (int mi = 0; mi < 4; ++mi) {                                            \
      const int row_ = wr * 128 + mi * 32 + l31;                                \
      dst_[mi] = *reinterpret_cast<const i32x4*>(                               \
          &As[buf_][row_ * 64 + (((ks_) * 2 + lhi) ^ ((row_ >> 1) & 3)) * 16]); \
    }                                                                           \
  } while (0)

#define READB_K(dst_, buf_, ks_) do {                                           \
    _Pragma("unroll")                                                           \
    for (int ni = 0; ni < 2; ++ni) {                                            \
      const int row_ = wc * 64 + ni * 32 + l31;                                 \
      dst_[ni] = *reinterpret_cast<const i32x4*>(                               \
          &Bs[buf_][row_ * 64 + (((ks_) * 2 + lhi) ^ ((row_ >> 1) & 3)) * 16]); \
    }                                                                           \
  } while (0)

// 8 MFMA of 32x32x32: all 4 m-frags x 2 n-frags for one kstep
#define MMA8(areg_, breg_) do {                                                 \
    __builtin_amdgcn_s_setprio(1);                                              \
    _Pragma("unroll")                                                           \
    for (int mi = 0; mi < 4; ++mi) {                                            \
      _Pragma("unroll")                                                         \
      for (int ni = 0; ni < 2; ++ni) {                                          \
        acc[mi][ni] = __builtin_amdgcn_mfma_i32_32x32x32_i8(                    \
            areg_[mi], breg_[ni], acc[mi][ni], 0, 0, 0);                        \
      }                                                                         \
    }                                                                           \
    __builtin_amdgcn_s_setprio(0);                                              \
  } while (0)

#define BAR() __builtin_amdgcn_s_barrier()
#define LGKM0() asm volatile("s_waitcnt lgkmcnt(0)" ::: "memory")

#define TILE(T_, buf_) do {                                                     \
    /* ph1 — A(T+1) overwrite legal: As[buf^1] consumed by tile T-1 */          \
    READA_K(aK0, buf_, 0);                                                      \
    READB_K(bK0, buf_, 0);                                                      \
    READB_K(bK1, buf_, 1);                                                      \
    ISSUE_H((T_) + 1, 0);                                                       \
    ISSUE_H((T_) + 1, 2);                                                       \
    MMA8(aK0, bK0);                                                             \
    LGKM0();  /* drain bK1 (consumed ph2) before BAR: overwrite anchor */       \
    BAR();                                                                      \
    /* ph2 — B(T+2) overwrite legal: all Bs[buf] reads drained at ph1 */        \
    READA_K(aK1, buf_, 1);                                                      \
    ISSUE_H((T_) + 2, 1);                                                       \
    ISSUE_H((T_) + 2, 3);                                                       \
    MMA8(aK1, bK1);                                                             \
    if ((T_) < NKT - 2)                                                         \
      asm volatile("s_waitcnt vmcnt(2)" ::: "memory");                          \
    else                                                                        \
      asm volatile("s_waitcnt vmcnt(0)" ::: "memory");                          \
    BAR();                                                                      \
  } while (0)

  // prologue: A(0) + B(0) + B(1), 6 loads, stream order matches steady state.
  // vmcnt(2) => A(0), B(0) landed (B(1) may remain in flight).
  ISSUE_H(0, 0); ISSUE_H(0, 2); ISSUE_H(0, 1); ISSUE_H(0, 3);
  ISSUE_H(1, 1); ISSUE_H(1, 3);
  asm volatile("s_waitcnt vmcnt(2)" ::: "memory");
  __builtin_amdgcn_s_barrier();

  for (int T = 0; T < NKT; T += 2) {
    TILE(T, 0);
    TILE(T + 1, 1);
  }

  // epilogue: 32x32 C/D map col=lane&31, row=(reg&3)+8*(reg>>2)+4*(lane>>5)
  // (m74/m101-verified, dtype-independent)
#pragma unroll
  for (int ni = 0; ni < 2; ++ni) {
    const int col = n0 + wc * 64 + ni * 32 + l31;
    const float sc = scale[col];
    const float bs = bias[col];
#pragma unroll
    for (int mi = 0; mi < 4; ++mi) {
      const int rbase = m0 + wr * 128 + mi * 32 + 4 * lhi;
#pragma unroll
      for (int g = 0; g < 4; ++g) {
#pragma unroll
        for (int e = 0; e < 4; ++e) {
          const int row = rbase + g * 8 + e;
          const float xs = XS[row];
          out[(size_t)row * DOUT + col] =
              (float)acc[mi][ni][g * 4 + e] * (xs * sc) + bs;
        }
      }
    }
  }
#undef ISSUE_H
#undef READA_K
#undef READB_K
#undef MMA8
#undef BAR
#undef LGKM0
#undef TILE
}

extern "C" void kernel_launch(void* const* d_in, const int* in_sizes, int n_in,
                              void* d_out, int out_size, void* d_ws, size_t ws_size,
                              hipStream_t stream) {
  const float* X     = (const float*)d_in[0];
  const float* W     = (const float*)d_in[1];
  const float* scale = (const float*)d_in[2];
  const float* bias  = (const float*)d_in[3];
  float* out = (float*)d_out;

  // ws layout: QW i8 16 MB | XQ i8 32 MB | XS fp32 32 KB
  int8_t* QW = (int8_t*)d_ws;
  int8_t* XQ = (int8_t*)d_ws + (size_t)DOUT * DIN;
  float*  XS = (float*)((int8_t*)d_ws + (size_t)DOUT * DIN + (size_t)MTOT * DIN);

  quant_w<<<DOUT, 256, 0, stream>>>(W, QW);
  quant_x<<<MTOT, 256, 0, stream>>>(X, XQ, XS);
  dim3 grid(MTOT / 256, DOUT / 256);
  gemm256_i8<<<grid, 512, 0, stream>>>(XQ, QW, XS, scale, bias, out);
}

// Round 14
// 200.312 us; speedup vs baseline: 1.1278x; 1.0321x over previous
//
#include <hip/hip_runtime.h>
#include <hip/hip_bf16.h>
#include <stdint.h>

#define DIN   4096
#define DOUT  4096
#define MTOT  8192

#define BK    64
#define NKT   (DIN / BK)   // 64 K-tiles

typedef int i32x4 __attribute__((ext_vector_type(4)));

__device__ __forceinline__ void glds16(const void* g, void* l) {
  __builtin_amdgcn_global_load_lds(
      (__attribute__((address_space(1))) void*)g,
      (__attribute__((address_space(3))) void*)l, 16, 0, 0);
}

// ---------------------------------------------------------------------------
// Kernel 1: per-row alpha (fp64 accumulate) + ternary quantize -> i8 {-1,0,1}
// ---------------------------------------------------------------------------
__global__ __launch_bounds__(256) void quant_w(const float* __restrict__ W,
                                               int8_t* __restrict__ QW) {
  const int row = blockIdx.x;
  const int t = threadIdx.x;
  const float* wr = W + (size_t)row * DIN;

  float4 v[4];
  double s = 0.0;
#pragma unroll
  for (int j = 0; j < 4; ++j) {
    v[j] = reinterpret_cast<const float4*>(wr)[j * 256 + t];
    s += (double)fabsf(v[j].x) + (double)fabsf(v[j].y) +
         (double)fabsf(v[j].z) + (double)fabsf(v[j].w);
  }
#pragma unroll
  for (int off = 32; off > 0; off >>= 1) s += __shfl_down(s, off, 64);

  __shared__ double ssum[4];
  __shared__ float salpha;
  if ((t & 63) == 0) ssum[t >> 6] = s;
  __syncthreads();
  if (t == 0) salpha = (float)((ssum[0] + ssum[1] + ssum[2] + ssum[3]) / (double)DIN);
  __syncthreads();
  const float alpha = salpha;

  int* qo = reinterpret_cast<int*>(QW + (size_t)row * DIN);
#pragma unroll
  for (int j = 0; j < 4; ++j) {
    int q0 = v[j].x > alpha ? 1 : (v[j].x < -alpha ? -1 : 0);
    int q1 = v[j].y > alpha ? 1 : (v[j].y < -alpha ? -1 : 0);
    int q2 = v[j].z > alpha ? 1 : (v[j].z < -alpha ? -1 : 0);
    int q3 = v[j].w > alpha ? 1 : (v[j].w < -alpha ? -1 : 0);
    qo[j * 256 + t] =
        (q0 & 0xff) | ((q1 & 0xff) << 8) | ((q2 & 0xff) << 16) | ((q3 & 0xff) << 24);
  }
}

// ---------------------------------------------------------------------------
// Kernel 2: x fp32 -> i8 with per-row scale. xq = rint(x * 127/rowmax),
// XS[row] = rowmax/127.
// ---------------------------------------------------------------------------
__global__ __launch_bounds__(256) void quant_x(const float* __restrict__ X,
                                               int8_t* __restrict__ XQ,
                                               float* __restrict__ XS) {
  const int row = blockIdx.x;
  const int t = threadIdx.x;
  const float* xr = X + (size_t)row * DIN;

  float4 v[4];
  float mx = 0.f;
#pragma unroll
  for (int j = 0; j < 4; ++j) {
    v[j] = reinterpret_cast<const float4*>(xr)[j * 256 + t];
    mx = fmaxf(mx, fmaxf(fmaxf(fabsf(v[j].x), fabsf(v[j].y)),
                         fmaxf(fabsf(v[j].z), fabsf(v[j].w))));
  }
#pragma unroll
  for (int off = 32; off > 0; off >>= 1) mx = fmaxf(mx, __shfl_down(mx, off, 64));

  __shared__ float smax[4];
  __shared__ float sinv, ssc;
  if ((t & 63) == 0) smax[t >> 6] = mx;
  __syncthreads();
  if (t == 0) {
    float rm = fmaxf(fmaxf(smax[0], smax[1]), fmaxf(smax[2], smax[3]));
    sinv = rm > 0.f ? 127.f / rm : 0.f;
    ssc  = rm > 0.f ? rm / 127.f : 0.f;
  }
  __syncthreads();
  const float inv = sinv;
  if (t == 0) XS[row] = ssc;

  int* qo = reinterpret_cast<int*>(XQ + (size_t)row * DIN);
#pragma unroll
  for (int j = 0; j < 4; ++j) {
    int q0 = (int)rintf(v[j].x * inv);
    int q1 = (int)rintf(v[j].y * inv);
    int q2 = (int)rintf(v[j].z * inv);
    int q3 = (int)rintf(v[j].w * inv);
    qo[j * 256 + t] =
        (q0 & 0xff) | ((q1 & 0xff) << 8) | ((q2 & 0xff) << 16) | ((q3 & 0xff) << 24);
  }
}

// ---------------------------------------------------------------------------
// Kernel 3: 256x256 i8 MFMA GEMM (mfma_i32_16x16x64_i8), round-14:
// occupancy-fixed geometry. 1024 thr = 16 waves (4Mx4N), wave owns 64x64
// (acc = 16 x i32x4 = 64 AGPR, frags ~32 VGPR -> ~100 regs/wave ->
// 4 waves/SIMD, 2 blocks/CU = 32 waves/CU, TWO barrier domains).
// LDS: A/B [256 rows][64 B] i8 dbuf = 64 KB/block. One glds16/thread stages
// a whole 256x64 operand tile (16 KB = 1024 chunks).
//
// 2 windows/tile (r11-proven invariant):
//   ph1: read a[4]+b[4] (8 ds_read, r11 conflict-free pattern);
//        ISSUE A(T+1); MMA ni={0,1} (8); BAR
//   ph2: ISSUE B(T+2); MMA ni={2,3} (8); vmcnt(1|0); BAR
//
// Overwrite audit:
//   A(T+1)->As[buf^1]@ph1: As[buf^1] LDS reads were (T-1).ph1, consumed by
//     (T-1).ph1's MMA before its BAR; issuer crossed (T-1).ph2 BAR.     OK
//   B(T+2)->Bs[buf]@ph2: all Bs[buf] reads at T.ph1, consumed by T.ph1's
//     MMA before T.ph1's BAR; issue after.                              OK
//   Tile T+1 reads gated by T.ph2's vmcnt+BAR.                          OK
// vmcnt ledger (per-wave stream: ...B(T+1)@(T-1).ph2 < A(T+1)@T.ph1 <
//   B(T+2)@T.ph2, 1 instr each): at T.ph2 wait, vmcnt(1) => everything
//   through A(T+1) landed. vmcnt(0) for T >= NKT-2.
// Swizzle: 16B chunk ^ ((row>>1)&3) (r9-r11: measured 0 conflicts).
// ---------------------------------------------------------------------------
__global__ __launch_bounds__(1024, 4) void gemm256_i8(
    const int8_t* __restrict__ XQ, const int8_t* __restrict__ QW,
    const float* __restrict__ XS, const float* __restrict__ scale,
    const float* __restrict__ bias, float* __restrict__ out) {
  __shared__ int8_t As[2][16384];  // 16 KB each buf (256 rows x 64 B)
  __shared__ int8_t Bs[2][16384];

  const int t = threadIdx.x;
  const int lane = t & 63;
  const int wid = t >> 6;
  const int wr = wid >> 2, wc = wid & 3;          // 4x4 wave grid
  const int m0 = blockIdx.x * 256;                // m fast-varying
  const int n0 = blockIdx.y * 256;

  const int8_t* ag = XQ + (size_t)m0 * DIN;
  const int8_t* bg = QW + (size_t)n0 * DIN;

  i32x4 acc[4][4] = {};            // [m-frag][n-frag], 64 AGPRs
  i32x4 a[4], b[4];

  const int r = lane & 15, kq = lane >> 4;        // frag row / 16B k-chunk
  const int srow = t >> 2;                        // staging row 0..255
  const int scol = ((t & 3) ^ ((srow >> 1) & 3)) * 16;  // inverse-swizzled src

// stage one full 256x64 operand tile (1 glds16/thread)
#define ISSUE_T(Tt_, isb_) do {                                                 \
    const int T_ = (Tt_);                                                       \
    if (T_ < NKT) {                                                             \
      const int bf_ = T_ & 1;                                                   \
      const int8_t* gb_ = (isb_) ? bg : ag;                                     \
      int8_t* lb_ = (isb_) ? &Bs[bf_][0] : &As[bf_][0];                         \
      glds16(gb_ + (size_t)srow * DIN + T_ * 64 + scol, lb_ + t * 16);          \
    }                                                                           \
  } while (0)

#define READA(buf_) do {                                                        \
    _Pragma("unroll")                                                           \
    for (int mi = 0; mi < 4; ++mi) {                                            \
      const int row_ = wr * 64 + mi * 16 + r;                                   \
      a[mi] = *reinterpret_cast<const i32x4*>(                                  \
          &As[buf_][row_ * 64 + (kq ^ ((row_ >> 1) & 3)) * 16]);                \
    }                                                                           \
  } while (0)

#define READB(buf_) do {                                                        \
    _Pragma("unroll")                                                           \
    for (int ni = 0; ni < 4; ++ni) {                                            \
      const int row_ = wc * 64 + ni * 16 + r;                                   \
      b[ni] = *reinterpret_cast<const i32x4*>(                                  \
          &Bs[buf_][row_ * 64 + (kq ^ ((row_ >> 1) & 3)) * 16]);                \
    }                                                                           \
  } while (0)

// 8 MFMA: all 4 m-frags x n-frags {nh*2, nh*2+1}
#define MMA8(nh_) do {                                                          \
    __builtin_amdgcn_s_setprio(1);                                              \
    _Pragma("unroll")                                                           \
    for (int mi = 0; mi < 4; ++mi) {                                            \
      _Pragma("unroll")                                                         \
      for (int ni = 0; ni < 2; ++ni) {                                          \
        acc[mi][(nh_) * 2 + ni] =                                               \
            __builtin_amdgcn_mfma_i32_16x16x64_i8(                              \
                a[mi], b[(nh_) * 2 + ni], acc[mi][(nh_) * 2 + ni], 0, 0, 0);    \
      }                                                                         \
    }                                                                           \
    __builtin_amdgcn_s_setprio(0);                                              \
  } while (0)

#define BAR() __builtin_amdgcn_s_barrier()

#define TILE(T_, buf_) do {                                                     \
    /* ph1 — A(T+1) overwrite legal: As[buf^1] consumed at (T-1).ph1 */         \
    READA(buf_);                                                                \
    READB(buf_);                                                                \
    ISSUE_T((T_) + 1, 0);                                                       \
    MMA8(0);                                                                    \
    BAR();                                                                      \
    /* ph2 — B(T+2) overwrite legal: Bs[buf] consumed at T.ph1 */               \
    ISSUE_T((T_) + 2, 1);                                                       \
    MMA8(1);                                                                    \
    if ((T_) < NKT - 2)                                                         \
      asm volatile("s_waitcnt vmcnt(1)" ::: "memory");                          \
    else                                                                        \
      asm volatile("s_waitcnt vmcnt(0)" ::: "memory");                          \
    BAR();                                                                      \
  } while (0)

  // prologue: A(0), B(0), B(1) — 3 glds/thread, stream order matches steady
  // state. vmcnt(1) => A(0), B(0) landed (B(1) may remain in flight).
  ISSUE_T(0, 0); ISSUE_T(0, 1); ISSUE_T(1, 1);
  asm volatile("s_waitcnt vmcnt(1)" ::: "memory");
  __builtin_amdgcn_s_barrier();

  for (int T = 0; T < NKT; T += 2) {
    TILE(T, 0);
    TILE(T + 1, 1);
  }

  // epilogue: C/D lane map col=lane&15, row=(lane>>4)*4+e (dtype-independent)
  const int q4 = lane >> 4;
#pragma unroll
  for (int ni = 0; ni < 4; ++ni) {
    const int col = n0 + wc * 64 + ni * 16 + r;
    const float sc = scale[col];
    const float bs = bias[col];
#pragma unroll
    for (int mi = 0; mi < 4; ++mi) {
      const int row = m0 + wr * 64 + mi * 16 + q4 * 4;
#pragma unroll
      for (int e = 0; e < 4; ++e) {
        const float xs = XS[row + e];
        out[(size_t)(row + e) * DOUT + col] =
            (float)acc[mi][ni][e] * (xs * sc) + bs;
      }
    }
  }
#undef ISSUE_T
#undef READA
#undef READB
#undef MMA8
#undef BAR
#undef TILE
}

extern "C" void kernel_launch(void* const* d_in, const int* in_sizes, int n_in,
                              void* d_out, int out_size, void* d_ws, size_t ws_size,
                              hipStream_t stream) {
  const float* X     = (const float*)d_in[0];
  const float* W     = (const float*)d_in[1];
  const float* scale = (const float*)d_in[2];
  const float* bias  = (const float*)d_in[3];
  float* out = (float*)d_out;

  // ws layout: QW i8 16 MB | XQ i8 32 MB | XS fp32 32 KB
  int8_t* QW = (int8_t*)d_ws;
  int8_t* XQ = (int8_t*)d_ws + (size_t)DOUT * DIN;
  float*  XS = (float*)((int8_t*)d_ws + (size_t)DOUT * DIN + (size_t)MTOT * DIN);

  quant_w<<<DOUT, 256, 0, stream>>>(W, QW);
  quant_x<<<MTOT, 256, 0, stream>>>(X, XQ, XS);
  dim3 grid(MTOT / 256, DOUT / 256);
  gemm256_i8<<<grid, 1024, 0, stream>>>(XQ, QW, XS, scale, bias, out);
}